// Round 2
// baseline (789.919 us; speedup 1.0000x reference)
//
#include <hip/hip_runtime.h>
#include <math.h>

// B=32, S=256, NU=4, ML=9, H=768, V=30522; T = NU*ML = 36; M = B*T = 1152.
#define BB_ 32
#define SS_ 256
#define HH_ 768
#define VV_ 30522
#define TT_ 36
#define MM_ 1152
#define NBLK_GRU 48

typedef __bf16 bf16x8 __attribute__((ext_vector_type(8)));
typedef __bf16 bf16x4 __attribute__((ext_vector_type(4)));
typedef float f32x4 __attribute__((ext_vector_type(4)));

__device__ __forceinline__ float sigmoidf_(float x) { return 1.f / (1.f + expf(-x)); }

// async global->LDS, 16B per lane; LDS dest is wave-uniform base + lane*16
__device__ __forceinline__ void async_load16(const void* g, void* l) {
  __builtin_amdgcn_global_load_lds(
      (const __attribute__((address_space(1))) void*)g,
      (__attribute__((address_space(3))) void*)l, 16, 0, 0);
}

// ---------------- fp32 -> bf16 bulk convert ----------------
__global__ __launch_bounds__(256) void cvt_bf16(const float* __restrict__ s,
                                                __bf16* __restrict__ d, int n4) {
  int i = blockIdx.x * 256 + threadIdx.x;
  if (i < n4) {
    float4 v = reinterpret_cast<const float4*>(s)[i];
    bf16x4 o;
    o[0] = (__bf16)v.x; o[1] = (__bf16)v.y; o[2] = (__bf16)v.z; o[3] = (__bf16)v.w;
    reinterpret_cast<bf16x4*>(d)[i] = o;
  }
}

// ---------------- build step inputs ws[tau*32+b][k] (bf16) ----------------
__global__ __launch_bounds__(256) void build_ws(const float* __restrict__ dec,
                                                const int* __restrict__ teacher,
                                                const float* __restrict__ embed,
                                                __bf16* __restrict__ wsbf) {
  int idx = blockIdx.x * 256 + threadIdx.x;
  if (idx >= MM_ * HH_) return;
  int m = idx / HH_, k = idx - m * HH_;
  int tau = m >> 5, b = m & 31;
  int u = tau / 9, tt = tau - u * 9;
  float v;
  if (tt == 0) v = dec[((size_t)b * 4 + u) * HH_ + k];
  else v = embed[(size_t)teacher[(b * 4 + u) * 9 + tt - 1] * HH_ + k];
  wsbf[idx] = (__bf16)v;
}

// ---------------- encg[b][s] = enc[b][s][:] . wgen[1536:2304] ----------------
__global__ __launch_bounds__(256) void enc_gate(const float* __restrict__ enc,
                                                const float* __restrict__ wgen,
                                                float* __restrict__ encg) {
  int row = blockIdx.x * 4 + (threadIdx.x >> 6);
  int lane = threadIdx.x & 63;
  const float* er = enc + (size_t)row * HH_;
  float ssum = 0.f;
#pragma unroll
  for (int i = 0; i < 12; ++i) ssum += er[i * 64 + lane] * wgen[1536 + i * 64 + lane];
  for (int off = 32; off; off >>= 1) ssum += __shfl_down(ssum, off);
  if (lane == 0) encg[row] = ssum;
}

// ---------------- m97-style bf16 GEMM: C[M][ldC] = A[M][768] * B[N][768]^T ----------------
// MODE 0: store fp32. MODE 1: store exp(min(c,60)) fp32 + atomic row-sum of exp.
template <int MODE>
__global__ __launch_bounds__(256) void gemm_bt2(const __bf16* __restrict__ A,
                                                const __bf16* __restrict__ Bm,
                                                float* __restrict__ C,
                                                float* __restrict__ rowsum,
                                                int Nreal, int ldC) {
  __shared__ __bf16 As[128 * 32];
  __shared__ __bf16 Bs[128 * 32];
  const int tid = threadIdx.x;
  const int lane = tid & 63, wave = tid >> 6;
  const int wm = wave >> 1, wn = wave & 1;
  const int q = lane >> 4, ln = lane & 15;
  const int m0 = blockIdx.y * 128, n0 = blockIdx.x * 128;
  const int srow = (wave << 5) + (lane >> 2);
  const int kc = lane & 3;
  const size_t aoff = (size_t)(m0 + srow) * HH_ + kc * 8;
  const size_t aoff2 = aoff + 16 * HH_;
  int br1 = n0 + srow;      if (br1 >= Nreal) br1 = Nreal - 1;
  int br2 = n0 + srow + 16; if (br2 >= Nreal) br2 = Nreal - 1;
  __bf16* lA1 = &As[srow * 32 + kc * 8];
  __bf16* lA2 = &As[(srow + 16) * 32 + kc * 8];
  __bf16* lB1 = &Bs[srow * 32 + kc * 8];
  __bf16* lB2 = &Bs[(srow + 16) * 32 + kc * 8];
  f32x4 acc[4][4] = {};
  for (int kb = 0; kb < 24; ++kb) {
    const int k0 = kb << 5;
    async_load16(A + aoff + k0, lA1);
    async_load16(A + aoff2 + k0, lA2);
    async_load16(Bm + (size_t)br1 * HH_ + kc * 8 + k0, lB1);
    async_load16(Bm + (size_t)br2 * HH_ + kc * 8 + k0, lB2);
    __syncthreads();
    bf16x8 af[4], bfr[4];
#pragma unroll
    for (int mi = 0; mi < 4; ++mi)
      af[mi] = *reinterpret_cast<const bf16x8*>(&As[(wm * 64 + mi * 16 + ln) * 32 + q * 8]);
#pragma unroll
    for (int ni = 0; ni < 4; ++ni)
      bfr[ni] = *reinterpret_cast<const bf16x8*>(&Bs[(wn * 64 + ni * 16 + ln) * 32 + q * 8]);
#pragma unroll
    for (int mi = 0; mi < 4; ++mi)
#pragma unroll
      for (int ni = 0; ni < 4; ++ni)
        acc[mi][ni] = __builtin_amdgcn_mfma_f32_16x16x32_bf16(af[mi], bfr[ni], acc[mi][ni], 0, 0, 0);
    __syncthreads();
  }
#pragma unroll
  for (int mi = 0; mi < 4; ++mi)
#pragma unroll
    for (int r2 = 0; r2 < 4; ++r2) {
      const int m = m0 + wm * 64 + mi * 16 + q * 4 + r2;
      if (MODE == 0) {
#pragma unroll
        for (int ni = 0; ni < 4; ++ni) {
          int n = n0 + wn * 64 + ni * 16 + ln;
          if (n < Nreal) C[(size_t)m * ldC + n] = acc[mi][ni][r2];
        }
      } else {
        float part = 0.f;
#pragma unroll
        for (int ni = 0; ni < 4; ++ni) {
          int n = n0 + wn * 64 + ni * 16 + ln;
          float e = expf(fminf(acc[mi][ni][r2], 60.f));
          if (n < Nreal) { C[(size_t)m * ldC + n] = e; part += e; }
        }
#pragma unroll
        for (int o = 1; o < 16; o <<= 1) part += __shfl_xor(part, o);
        if (ln == 0) atomicAdd(rowsum + m, part);
      }
    }
}

// ---------------- persistent GRU scan v4 ----------------
// 48 blocks x 128. Whh slice XOR-swizzled in LDS; h carried in registers;
// cross-block h exchange via Hx dbuf (relaxed agent sc1 stores).
// Barrier v4: ONE monotonic counter (relaxed agent atomicAdd, 1 per block per
// step); ONLY wave 0 polls, all its lanes load the SAME address (one coalesced
// request per block per poll round). Wave 1 parks on __syncthreads. One
// acquire fence per step after the barrier.
__global__ __launch_bounds__(128, 1) void gru_scan(const __bf16* __restrict__ hid_bf,
                                                   const float* __restrict__ H0,
                                                   const __bf16* __restrict__ Whh,
                                                   const float* __restrict__ GI,
                                                   const float* __restrict__ bih,
                                                   const float* __restrict__ bhh,
                                                   __bf16* __restrict__ Ah,
                                                   __bf16* __restrict__ Hx,
                                                   unsigned* __restrict__ ctr) {
  __shared__ __bf16 WhhS[48 * HH_];   // 73,728 B
  const int tid = threadIdx.x, lane = tid & 63;
  const int mi = tid >> 6;            // wave id: b-tile (0:,16:)
  const int q = lane >> 4, ln = lane & 15;
  const int jH = blockIdx.x * 16 + ln;
  // stage Whh rows [g*768 + blk*16 + jl] -> LDS row g*16+jl, 16B chunk cs at cs^(row&7)
  for (int i = tid; i < 48 * 96; i += 128) {
    int row = i / 96, cs = i - row * 96;
    int g = row >> 4, jl = row & 15;
    bf16x8 v = *reinterpret_cast<const bf16x8*>(
        &Whh[((size_t)(g * 768 + blockIdx.x * 16 + jl)) * HH_ + cs * 8]);
    *reinterpret_cast<bf16x8*>(&WhhS[row * HH_ + ((cs ^ (row & 7)) * 8)]) = v;
  }
  const float bir = bih[jH], biz = bih[jH + 768], bin_ = bih[jH + 1536];
  const float bhr = bhh[jH], bhz = bhh[jH + 768], bhn = bhh[jH + 1536];
  // carry h in registers: this thread owns (b = mi*16+q*4+r2, jH)
  float hc[4];
#pragma unroll
  for (int r2 = 0; r2 < 4; ++r2)
    hc[r2] = H0[(size_t)(mi * 16 + q * 4 + r2) * HH_ + jH];
  const __bf16* w0 = &WhhS[(0 + ln) * HH_];
  const __bf16* w1 = &WhhS[(16 + ln) * HH_];
  const __bf16* w2 = &WhhS[(32 + ln) * HH_];
  const int swz = (ln & 7) * 8;       // XOR swizzle in bf16 units (chunk^= ln&7)
  // GI for tau=0 preloaded into registers
  float gir[4], giz[4], gin[4];
#pragma unroll
  for (int r2 = 0; r2 < 4; ++r2) {
    const float* gi = GI + (size_t)(mi * 16 + q * 4 + r2) * 2304;
    gir[r2] = gi[jH]; giz[r2] = gi[jH + 768]; gin[r2] = gi[jH + 1536];
  }
  __syncthreads();
  for (int tau = 0; tau < TT_; ++tau) {
    const __bf16* arow = tau ? (Hx + (size_t)(((tau - 1) & 1) * 32 + mi * 16 + ln) * HH_)
                             : (hid_bf + (size_t)(mi * 16 + ln) * HH_);
    // issue all 24 A chunks up front (full memory-level parallelism)
    bf16x8 areg[24];
#pragma unroll
    for (int kb = 0; kb < 24; ++kb)
      areg[kb] = *reinterpret_cast<const bf16x8*>(arow + kb * 32 + q * 8);
    f32x4 a0 = {}, a1 = {}, a2 = {};
#pragma unroll
    for (int kb = 0; kb < 24; ++kb) {
      int kl = (kb * 32 + q * 8) ^ swz;
      bf16x8 b0 = *reinterpret_cast<const bf16x8*>(w0 + kl);
      bf16x8 b1 = *reinterpret_cast<const bf16x8*>(w1 + kl);
      bf16x8 b2 = *reinterpret_cast<const bf16x8*>(w2 + kl);
      a0 = __builtin_amdgcn_mfma_f32_16x16x32_bf16(areg[kb], b0, a0, 0, 0, 0);
      a1 = __builtin_amdgcn_mfma_f32_16x16x32_bf16(areg[kb], b1, a1, 0, 0, 0);
      a2 = __builtin_amdgcn_mfma_f32_16x16x32_bf16(areg[kb], b2, a2, 0, 0, 0);
    }
    __bf16* hxc = Hx + (size_t)((tau & 1) * 32) * HH_;
#pragma unroll
    for (int r2 = 0; r2 < 4; ++r2) {
      int b = mi * 16 + q * 4 + r2;
      float r = sigmoidf_(gir[r2] + bir + a0[r2] + bhr);
      float z = sigmoidf_(giz[r2] + biz + a1[r2] + bhz);
      float n = tanhf(gin[r2] + bin_ + r * (a2[r2] + bhn));
      float h = (1.f - z) * n + z * hc[r2];
      hc[r2] = h;
      // pack (jH, jH+1) bf16 pair into u32 via lane^1 exchange; even lanes store
      float hp = __shfl_xor(h, 1);
      __bf16 hb = (__bf16)h, hpb = (__bf16)hp;
      unsigned lo = (unsigned)__builtin_bit_cast(unsigned short, hb);
      unsigned hi = (unsigned)__builtin_bit_cast(unsigned short, hpb);
      if (!(ln & 1)) {
        unsigned u = lo | (hi << 16);
        // Ah for downstream kernels: plain cached store (visible at kernel end)
        *reinterpret_cast<unsigned*>(&Ah[((size_t)b * TT_ + tau) * HH_ + jH]) = u;
        // Hx for the cross-block scan: coherence-point store (sc1)
        if (tau < TT_ - 1)
          __hip_atomic_store(reinterpret_cast<unsigned*>(&hxc[(size_t)b * HH_ + jH]), u,
                             __ATOMIC_RELAXED, __HIP_MEMORY_SCOPE_AGENT);
      }
    }
    if (tau < TT_ - 1) {
      __syncthreads();   // drains vmcnt: all Hx sc1-stores at coherence point
      if (tid == 0)
        __hip_atomic_fetch_add(ctr, 1u, __ATOMIC_RELAXED, __HIP_MEMORY_SCOPE_AGENT);
      // prefetch GI for tau+1 now; latency hides inside the barrier wait
      {
        const float* GIt = GI + (size_t)(tau + 1) * BB_ * 2304;
#pragma unroll
        for (int r2 = 0; r2 < 4; ++r2) {
          const float* gi = GIt + (size_t)(mi * 16 + q * 4 + r2) * 2304;
          gir[r2] = gi[jH]; giz[r2] = gi[jH + 768]; gin[r2] = gi[jH + 1536];
        }
      }
      if (mi == 0) {       // only wave 0 polls; one coalesced same-address load
        const unsigned tgt = (unsigned)(tau + 1) * NBLK_GRU;
        int spin = 0;
        while (__hip_atomic_load(ctr, __ATOMIC_RELAXED, __HIP_MEMORY_SCOPE_AGENT) < tgt) {
          __builtin_amdgcn_s_sleep(1);
          if (++spin > (1 << 20)) break;   // fail loud, don't wedge
        }
      }
      __syncthreads();     // wave 1 parks here until wave 0's poll succeeds
      __builtin_amdgcn_fence(__ATOMIC_ACQUIRE, "agent");  // one inv per step
    }
  }
}

// ---------------- attention scores E[b*36+tau][s] (batched MFMA) ----------------
__global__ __launch_bounds__(256) void attn_gemm(const __bf16* __restrict__ Ah,
                                                 const __bf16* __restrict__ encb,
                                                 float* __restrict__ E) {
  int b = blockIdx.x >> 2, stile = blockIdx.x & 3;
  int wave = threadIdx.x >> 6, lane = threadIdx.x & 63;
  int q = lane >> 4, ln = lane & 15;
  int s = stile * 64 + wave * 16 + ln;
  const __bf16* brow = encb + ((size_t)b * SS_ + s) * HH_;
  const __bf16* arow[3];
#pragma unroll
  for (int mt = 0; mt < 3; ++mt) {
    int tau = mt * 16 + ln; if (tau > 35) tau = 35;
    arow[mt] = Ah + ((size_t)b * TT_ + tau) * HH_;
  }
  f32x4 acc[3] = {};
#pragma unroll 4
  for (int kb = 0; kb < 24; ++kb) {
    int k0 = kb * 32 + q * 8;
    bf16x8 bb = *reinterpret_cast<const bf16x8*>(brow + k0);
#pragma unroll
    for (int mt = 0; mt < 3; ++mt) {
      bf16x8 aa = *reinterpret_cast<const bf16x8*>(arow[mt] + k0);
      acc[mt] = __builtin_amdgcn_mfma_f32_16x16x32_bf16(aa, bb, acc[mt], 0, 0, 0);
    }
  }
#pragma unroll
  for (int mt = 0; mt < 3; ++mt)
#pragma unroll
    for (int r2 = 0; r2 < 4; ++r2) {
      int tau = mt * 16 + q * 4 + r2;
      if (tau < 36) E[((size_t)b * TT_ + tau) * SS_ + s] = acc[mt][r2];
    }
}

// ---------------- masked softmax over S + p_gen ----------------
__global__ __launch_bounds__(256) void softmax_pg(const float* __restrict__ E,
                                                  const int* __restrict__ x,
                                                  const float* __restrict__ encg,
                                                  const __bf16* __restrict__ wsbf,
                                                  const __bf16* __restrict__ Ah,
                                                  const float* __restrict__ wgen,
                                                  const float* __restrict__ wgenb,
                                                  float* __restrict__ attn,
                                                  float* __restrict__ pg) {
  int m = blockIdx.x;
  int b = m / TT_, tau = m - b * TT_;
  int m_in = tau * 32 + b;
  int t = threadIdx.x;
  __shared__ float red[256];
  __shared__ float r1[256], r2[256], r3[256];
  float e = E[(size_t)m * SS_ + t];
  if (x[b * SS_ + t] == 0) e = -1000000000.0f;
  red[t] = e; __syncthreads();
  for (int off = 128; off; off >>= 1) {
    if (t < off) red[t] = fmaxf(red[t], red[t + off]);
    __syncthreads();
  }
  float mx = red[0];
  float p = expf(e - mx);
  float dsum = 0.f;
#pragma unroll
  for (int i = 0; i < 3; ++i) {
    int k = t + i * 256;
    dsum += (float)wsbf[(size_t)m_in * HH_ + k] * wgen[k];
    dsum += (float)Ah[(size_t)m * HH_ + k] * wgen[768 + k];
  }
  float pe = p * encg[b * SS_ + t];
  r1[t] = p; r2[t] = pe; r3[t] = dsum; __syncthreads();
  for (int off = 128; off; off >>= 1) {
    if (t < off) { r1[t] += r1[t + off]; r2[t] += r2[t + off]; r3[t] += r3[t + off]; }
    __syncthreads();
  }
  float Z = r1[0];
  attn[(size_t)m * SS_ + t] = p / Z;
  if (t == 0) pg[m] = sigmoidf_(r3[0] + r2[0] / Z + wgenb[0]);
}

// ---------------- finalize: out = pg/Z * exp_vals (in place) ----------------
__global__ __launch_bounds__(256) void finalize(float* __restrict__ C,
                                                const float* __restrict__ rowsum,
                                                const float* __restrict__ pg) {
  int m = blockIdx.y;
  float scale = pg[m] / rowsum[m];
  int base_i = blockIdx.x * 2048;
  size_t rowb = (size_t)m * VV_;
#pragma unroll
  for (int j = 0; j < 8; ++j) {
    int i = base_i + j * 256 + threadIdx.x;
    if (i < VV_) C[rowb + i] *= scale;
  }
}

// ---------------- pointer scatter ----------------
__global__ __launch_bounds__(256) void scatter_ctx(float* __restrict__ C,
                                                   const float* __restrict__ attn,
                                                   const float* __restrict__ pg,
                                                   const int* __restrict__ x) {
  int m = blockIdx.x, s = threadIdx.x;
  int b = m / TT_;
  float v = (1.f - pg[m]) * attn[(size_t)m * SS_ + s];
  int col = x[b * SS_ + s];
  atomicAdd(C + (size_t)m * VV_ + col, v);
}

extern "C" void kernel_launch(void* const* d_in, const int* in_sizes, int n_in,
                              void* d_out, int out_size, void* d_ws, size_t ws_size,
                              hipStream_t stream) {
  const int*   x       = (const int*)d_in[0];
  const float* dec     = (const float*)d_in[1];
  const float* enc     = (const float*)d_in[2];
  const float* hidden  = (const float*)d_in[3];
  const int*   teacher = (const int*)d_in[5];
  const float* embed   = (const float*)d_in[6];
  const float* wih     = (const float*)d_in[7];
  const float* whh     = (const float*)d_in[8];
  const float* bih     = (const float*)d_in[9];
  const float* bhh     = (const float*)d_in[10];
  const float* wgen    = (const float*)d_in[11];
  const float* wgenb   = (const float*)d_in[12];
  float* out = (float*)d_out;

  char* w = (char*)d_ws;
  __bf16* embed_bf = (__bf16*)w;  w += (size_t)VV_ * HH_ * 2;
  __bf16* enc_bf   = (__bf16*)w;  w += (size_t)BB_ * SS_ * HH_ * 2;
  __bf16* wih_bf   = (__bf16*)w;  w += (size_t)2304 * HH_ * 2;
  __bf16* whh_bf   = (__bf16*)w;  w += (size_t)2304 * HH_ * 2;
  __bf16* ws_bf    = (__bf16*)w;  w += (size_t)MM_ * HH_ * 2;
  __bf16* hid_bf   = (__bf16*)w;  w += (size_t)BB_ * HH_ * 2;
  __bf16* A_h      = (__bf16*)w;  w += (size_t)MM_ * HH_ * 2;
  float*  GI       = (float*)w;   w += (size_t)MM_ * 2304 * 4;
  float*  E        = (float*)w;   w += (size_t)MM_ * SS_ * 4;
  float*  attn     = (float*)w;   w += (size_t)MM_ * SS_ * 4;
  float*  encg     = (float*)w;   w += (size_t)BB_ * SS_ * 4;
  float*  pg       = (float*)w;   w += 8192;
  char*   ctl      = w;           w += 8192;   // rowsum[1152] + ctr
  __bf16* Hx       = (__bf16*)w;  w += (size_t)2 * BB_ * HH_ * 2;  // h exchange dbuf
  float*    rowsum = (float*)ctl;
  unsigned* ctr    = (unsigned*)(ctl + 4864);

  // 0) zero rowsum + ctr (ws is re-poisoned 0xAA before every call)
  hipMemsetAsync(ctl, 0, 8192, stream);

  // 1) conversions to bf16
  cvt_bf16<<<(VV_ * HH_ / 4 + 255) / 256, 256, 0, stream>>>(embed, embed_bf, VV_ * HH_ / 4);
  cvt_bf16<<<(BB_ * SS_ * HH_ / 4 + 255) / 256, 256, 0, stream>>>(enc, enc_bf, BB_ * SS_ * HH_ / 4);
  cvt_bf16<<<(2304 * HH_ / 4 + 255) / 256, 256, 0, stream>>>(wih, wih_bf, 2304 * HH_ / 4);
  cvt_bf16<<<(2304 * HH_ / 4 + 255) / 256, 256, 0, stream>>>(whh, whh_bf, 2304 * HH_ / 4);
  cvt_bf16<<<(BB_ * HH_ / 4 + 255) / 256, 256, 0, stream>>>(hidden, hid_bf, BB_ * HH_ / 4);

  // 2) step inputs
  build_ws<<<(MM_ * HH_ + 255) / 256, 256, 0, stream>>>(dec, teacher, embed, ws_bf);

  // 3) GI = ws @ Wih^T : M=1152, N=2304, K=768
  gemm_bt2<0><<<dim3(2304 / 128, MM_ / 128), 256, 0, stream>>>(ws_bf, wih_bf, GI, nullptr, 2304, 2304);

  // 4) encg
  enc_gate<<<BB_ * SS_ / 4, 256, 0, stream>>>(enc, wgen, encg);

  // 5) persistent GRU scan (single-counter barrier, one polling wave)
  gru_scan<<<NBLK_GRU, 128, 0, stream>>>(hid_bf, hidden, whh_bf, GI, bih, bhh, A_h, Hx, ctr);

  // 6) attention + masked softmax + p_gen
  attn_gemm<<<BB_ * 4, 256, 0, stream>>>(A_h, enc_bf, E);
  softmax_pg<<<MM_, 256, 0, stream>>>(E, x, encg, ws_bf, A_h, wgen, wgenb, attn, pg);

  // 7) vocab logits -> exp into d_out + atomic row sums
  gemm_bt2<1><<<dim3((VV_ + 127) / 128, MM_ / 128), 256, 0, stream>>>(A_h, embed_bf, out, rowsum, VV_, VV_);

  // 8) scale by pg/Z in place, then pointer scatter
  finalize<<<dim3((VV_ + 2047) / 2048, MM_), 256, 0, stream>>>(out, rowsum, pg);
  scatter_ctx<<<MM_, 256, 0, stream>>>(out, attn, pg, x);
}

// Round 3
// 763.458 us; speedup vs baseline: 1.0347x; 1.0347x over previous
//
#include <hip/hip_runtime.h>
#include <math.h>

// B=32, S=256, NU=4, ML=9, H=768, V=30522; T = NU*ML = 36; M = B*T = 1152.
#define BB_ 32
#define SS_ 256
#define HH_ 768
#define VV_ 30522
#define TT_ 36
#define MM_ 1152
#define NBLK_GRU 48

typedef __bf16 bf16x8 __attribute__((ext_vector_type(8)));
typedef __bf16 bf16x4 __attribute__((ext_vector_type(4)));
typedef float f32x4 __attribute__((ext_vector_type(4)));
typedef unsigned int u32x4 __attribute__((ext_vector_type(4)));

__device__ __forceinline__ float sigmoidf_(float x) { return 1.f / (1.f + expf(-x)); }

// async global->LDS, 16B per lane; LDS dest is wave-uniform base + lane*16
__device__ __forceinline__ void async_load16(const void* g, void* l) {
  __builtin_amdgcn_global_load_lds(
      (const __attribute__((address_space(1))) void*)g,
      (__attribute__((address_space(3))) void*)l, 16, 0, 0);
}

// ---------------- fp32 -> bf16 bulk convert ----------------
__global__ __launch_bounds__(256) void cvt_bf16(const float* __restrict__ s,
                                                __bf16* __restrict__ d, int n4) {
  int i = blockIdx.x * 256 + threadIdx.x;
  if (i < n4) {
    float4 v = reinterpret_cast<const float4*>(s)[i];
    bf16x4 o;
    o[0] = (__bf16)v.x; o[1] = (__bf16)v.y; o[2] = (__bf16)v.z; o[3] = (__bf16)v.w;
    reinterpret_cast<bf16x4*>(d)[i] = o;
  }
}

// ---------------- build step inputs ws[tau*32+b][k] (bf16) ----------------
__global__ __launch_bounds__(256) void build_ws(const float* __restrict__ dec,
                                                const int* __restrict__ teacher,
                                                const float* __restrict__ embed,
                                                __bf16* __restrict__ wsbf) {
  int idx = blockIdx.x * 256 + threadIdx.x;
  if (idx >= MM_ * HH_) return;
  int m = idx / HH_, k = idx - m * HH_;
  int tau = m >> 5, b = m & 31;
  int u = tau / 9, tt = tau - u * 9;
  float v;
  if (tt == 0) v = dec[((size_t)b * 4 + u) * HH_ + k];
  else v = embed[(size_t)teacher[(b * 4 + u) * 9 + tt - 1] * HH_ + k];
  wsbf[idx] = (__bf16)v;
}

// ---------------- encg[b][s] = enc[b][s][:] . wgen[1536:2304] ----------------
__global__ __launch_bounds__(256) void enc_gate(const float* __restrict__ enc,
                                                const float* __restrict__ wgen,
                                                float* __restrict__ encg) {
  int row = blockIdx.x * 4 + (threadIdx.x >> 6);
  int lane = threadIdx.x & 63;
  const float* er = enc + (size_t)row * HH_;
  float ssum = 0.f;
#pragma unroll
  for (int i = 0; i < 12; ++i) ssum += er[i * 64 + lane] * wgen[1536 + i * 64 + lane];
  for (int off = 32; off; off >>= 1) ssum += __shfl_down(ssum, off);
  if (lane == 0) encg[row] = ssum;
}

// ---------------- m97-style bf16 GEMM: C[M][ldC] = A[M][768] * B[N][768]^T ----------------
// MODE 0: store fp32. MODE 1: store exp(min(c,60)) fp32 + atomic row-sum of exp.
template <int MODE>
__global__ __launch_bounds__(256) void gemm_bt2(const __bf16* __restrict__ A,
                                                const __bf16* __restrict__ Bm,
                                                float* __restrict__ C,
                                                float* __restrict__ rowsum,
                                                int Nreal, int ldC) {
  __shared__ __bf16 As[128 * 32];
  __shared__ __bf16 Bs[128 * 32];
  const int tid = threadIdx.x;
  const int lane = tid & 63, wave = tid >> 6;
  const int wm = wave >> 1, wn = wave & 1;
  const int q = lane >> 4, ln = lane & 15;
  const int m0 = blockIdx.y * 128, n0 = blockIdx.x * 128;
  const int srow = (wave << 5) + (lane >> 2);
  const int kc = lane & 3;
  const size_t aoff = (size_t)(m0 + srow) * HH_ + kc * 8;
  const size_t aoff2 = aoff + 16 * HH_;
  int br1 = n0 + srow;      if (br1 >= Nreal) br1 = Nreal - 1;
  int br2 = n0 + srow + 16; if (br2 >= Nreal) br2 = Nreal - 1;
  __bf16* lA1 = &As[srow * 32 + kc * 8];
  __bf16* lA2 = &As[(srow + 16) * 32 + kc * 8];
  __bf16* lB1 = &Bs[srow * 32 + kc * 8];
  __bf16* lB2 = &Bs[(srow + 16) * 32 + kc * 8];
  f32x4 acc[4][4] = {};
  for (int kb = 0; kb < 24; ++kb) {
    const int k0 = kb << 5;
    async_load16(A + aoff + k0, lA1);
    async_load16(A + aoff2 + k0, lA2);
    async_load16(Bm + (size_t)br1 * HH_ + kc * 8 + k0, lB1);
    async_load16(Bm + (size_t)br2 * HH_ + kc * 8 + k0, lB2);
    __syncthreads();
    bf16x8 af[4], bfr[4];
#pragma unroll
    for (int mi = 0; mi < 4; ++mi)
      af[mi] = *reinterpret_cast<const bf16x8*>(&As[(wm * 64 + mi * 16 + ln) * 32 + q * 8]);
#pragma unroll
    for (int ni = 0; ni < 4; ++ni)
      bfr[ni] = *reinterpret_cast<const bf16x8*>(&Bs[(wn * 64 + ni * 16 + ln) * 32 + q * 8]);
#pragma unroll
    for (int mi = 0; mi < 4; ++mi)
#pragma unroll
      for (int ni = 0; ni < 4; ++ni)
        acc[mi][ni] = __builtin_amdgcn_mfma_f32_16x16x32_bf16(af[mi], bfr[ni], acc[mi][ni], 0, 0, 0);
    __syncthreads();
  }
#pragma unroll
  for (int mi = 0; mi < 4; ++mi)
#pragma unroll
    for (int r2 = 0; r2 < 4; ++r2) {
      const int m = m0 + wm * 64 + mi * 16 + q * 4 + r2;
      if (MODE == 0) {
#pragma unroll
        for (int ni = 0; ni < 4; ++ni) {
          int n = n0 + wn * 64 + ni * 16 + ln;
          if (n < Nreal) C[(size_t)m * ldC + n] = acc[mi][ni][r2];
        }
      } else {
        float part = 0.f;
#pragma unroll
        for (int ni = 0; ni < 4; ++ni) {
          int n = n0 + wn * 64 + ni * 16 + ln;
          float e = expf(fminf(acc[mi][ni][r2], 60.f));
          if (n < Nreal) { C[(size_t)m * ldC + n] = e; part += e; }
        }
#pragma unroll
        for (int o = 1; o < 16; o <<= 1) part += __shfl_xor(part, o);
        if (ln == 0) atomicAdd(rowsum + m, part);
      }
    }
}

// ---------------- persistent GRU scan v5 ----------------
// 48 blocks x 128. Whh slice XOR-swizzled in LDS; h carried in registers;
// exchange via Hx dbuf (relaxed agent sc1 stores).
// v5 protocol: NO acquire fence / buffer_inv, NO __syncthreads in the loop.
// - Consumer A-loads are device-scope (sc1) global_load_dwordx4: read the
//   coherence point directly, so no cache invalidate is ever needed.
// - Release is per-wave: each wave drains its own stores (vmcnt(0)), then
//   lane 0 publishes a per-(block,wave) flag. Rows 0-15 / 16-31 form closed
//   systems per wave, so wave mi polls only the 48 same-mi flags.
// - Flag-after-drain guarantees data is at the MALL before the flag is
//   visible, so sc1 reads need no ordering op at all.
__global__ __launch_bounds__(128, 1) void gru_scan(const __bf16* __restrict__ hid_bf,
                                                   const float* __restrict__ H0,
                                                   const __bf16* __restrict__ Whh,
                                                   const float* __restrict__ GI,
                                                   const float* __restrict__ bih,
                                                   const float* __restrict__ bhh,
                                                   __bf16* __restrict__ Ah,
                                                   __bf16* __restrict__ Hx,
                                                   unsigned* __restrict__ flags) {
  __shared__ __bf16 WhhS[48 * HH_];   // 73,728 B
  const int tid = threadIdx.x, lane = tid & 63;
  const int mi = tid >> 6;            // wave id: b-tile (0:,16:)
  const int q = lane >> 4, ln = lane & 15;
  const int jH = blockIdx.x * 16 + ln;
  // stage Whh rows [g*768 + blk*16 + jl] -> LDS row g*16+jl, 16B chunk cs at cs^(row&7)
  for (int i = tid; i < 48 * 96; i += 128) {
    int row = i / 96, cs = i - row * 96;
    int g = row >> 4, jl = row & 15;
    bf16x8 v = *reinterpret_cast<const bf16x8*>(
        &Whh[((size_t)(g * 768 + blockIdx.x * 16 + jl)) * HH_ + cs * 8]);
    *reinterpret_cast<bf16x8*>(&WhhS[row * HH_ + ((cs ^ (row & 7)) * 8)]) = v;
  }
  const float bir = bih[jH], biz = bih[jH + 768], bin_ = bih[jH + 1536];
  const float bhr = bhh[jH], bhz = bhh[jH + 768], bhn = bhh[jH + 1536];
  // carry h in registers: this thread owns (b = mi*16+q*4+r2, jH)
  float hc[4];
#pragma unroll
  for (int r2 = 0; r2 < 4; ++r2)
    hc[r2] = H0[(size_t)(mi * 16 + q * 4 + r2) * HH_ + jH];
  const __bf16* w0 = &WhhS[(0 + ln) * HH_];
  const __bf16* w1 = &WhhS[(16 + ln) * HH_];
  const __bf16* w2 = &WhhS[(32 + ln) * HH_];
  const int swz = (ln & 7) * 8;       // XOR swizzle in bf16 units (chunk^= ln&7)
  // GI for tau=0 preloaded into registers
  float gir[4], giz[4], gin[4];
#pragma unroll
  for (int r2 = 0; r2 < 4; ++r2) {
    const float* gi = GI + (size_t)(mi * 16 + q * 4 + r2) * 2304;
    gir[r2] = gi[jH]; giz[r2] = gi[jH + 768]; gin[r2] = gi[jH + 1536];
  }
  __syncthreads();   // WhhS ready — the only barrier in this kernel
  for (int tau = 0; tau < TT_; ++tau) {
    const __bf16* arow = tau ? (Hx + (size_t)(((tau - 1) & 1) * 32 + mi * 16 + ln) * HH_)
                             : (hid_bf + (size_t)(mi * 16 + ln) * HH_);
    // A-fragment loads: device-scope (sc1) dwordx4 — fresh from the MALL,
    // same coalescing as a plain b128 load, no buffer_inv required.
    u32x4 raw[24];
#pragma unroll
    for (int kb = 0; kb < 24; ++kb) {
      const __bf16* ap = arow + kb * 32 + q * 8;
      asm volatile("global_load_dwordx4 %0, %1, off sc1"
                   : "=v"(raw[kb]) : "v"(ap) : "memory");
    }
    asm volatile("s_waitcnt vmcnt(0)" ::: "memory");
    __builtin_amdgcn_sched_barrier(0);
    f32x4 a0 = {}, a1 = {}, a2 = {};
#pragma unroll
    for (int kb = 0; kb < 24; ++kb) {
      bf16x8 a = __builtin_bit_cast(bf16x8, raw[kb]);
      int kl = (kb * 32 + q * 8) ^ swz;
      bf16x8 b0 = *reinterpret_cast<const bf16x8*>(w0 + kl);
      bf16x8 b1 = *reinterpret_cast<const bf16x8*>(w1 + kl);
      bf16x8 b2 = *reinterpret_cast<const bf16x8*>(w2 + kl);
      a0 = __builtin_amdgcn_mfma_f32_16x16x32_bf16(a, b0, a0, 0, 0, 0);
      a1 = __builtin_amdgcn_mfma_f32_16x16x32_bf16(a, b1, a1, 0, 0, 0);
      a2 = __builtin_amdgcn_mfma_f32_16x16x32_bf16(a, b2, a2, 0, 0, 0);
    }
    __bf16* hxc = Hx + (size_t)((tau & 1) * 32) * HH_;
#pragma unroll
    for (int r2 = 0; r2 < 4; ++r2) {
      int b = mi * 16 + q * 4 + r2;
      float r = sigmoidf_(gir[r2] + bir + a0[r2] + bhr);
      float z = sigmoidf_(giz[r2] + biz + a1[r2] + bhz);
      float n = tanhf(gin[r2] + bin_ + r * (a2[r2] + bhn));
      float h = (1.f - z) * n + z * hc[r2];
      hc[r2] = h;
      // pack (jH, jH+1) bf16 pair into u32 via lane^1 exchange; even lanes store
      float hp = __shfl_xor(h, 1);
      __bf16 hb = (__bf16)h, hpb = (__bf16)hp;
      unsigned lo = (unsigned)__builtin_bit_cast(unsigned short, hb);
      unsigned hi = (unsigned)__builtin_bit_cast(unsigned short, hpb);
      if (!(ln & 1)) {
        unsigned u = lo | (hi << 16);
        // Ah for downstream kernels: plain cached store (visible at kernel end)
        *reinterpret_cast<unsigned*>(&Ah[((size_t)b * TT_ + tau) * HH_ + jH]) = u;
        // Hx for the cross-block scan: coherence-point store (sc1)
        if (tau < TT_ - 1)
          __hip_atomic_store(reinterpret_cast<unsigned*>(&hxc[(size_t)b * HH_ + jH]), u,
                             __ATOMIC_RELAXED, __HIP_MEMORY_SCOPE_AGENT);
      }
    }
    if (tau < TT_ - 1) {
      // per-wave release: drain own sc1 stores, then publish per-wave flag
      asm volatile("s_waitcnt vmcnt(0)" ::: "memory");
      if (lane == 0)
        __hip_atomic_store(&flags[(size_t)(blockIdx.x * 2 + mi) * 16], (unsigned)(tau + 1),
                           __ATOMIC_RELAXED, __HIP_MEMORY_SCOPE_AGENT);
      // prefetch GI for tau+1 now; latency hides inside the poll
      {
        const float* GIt = GI + (size_t)(tau + 1) * BB_ * 2304;
#pragma unroll
        for (int r2 = 0; r2 < 4; ++r2) {
          const float* gi = GIt + (size_t)(mi * 16 + q * 4 + r2) * 2304;
          gir[r2] = gi[jH]; giz[r2] = gi[jH + 768]; gin[r2] = gi[jH + 1536];
        }
      }
      // poll only the 48 same-mi producer-wave flags
      const unsigned tgt = (unsigned)(tau + 1);
      int ok = 0, spin = 0;
      while (!ok) {
        unsigned v = (lane < NBLK_GRU)
            ? __hip_atomic_load(&flags[(size_t)(lane * 2 + mi) * 16], __ATOMIC_RELAXED,
                                __HIP_MEMORY_SCOPE_AGENT)
            : tgt;
        ok = __all((int)(v >= tgt));
        if (!ok) {
          __builtin_amdgcn_s_sleep(1);
          if (++spin > (1 << 20)) break;   // fail loud, don't wedge
        }
      }
    }
  }
}

// ---------------- attention scores E[b*36+tau][s] (batched MFMA) ----------------
__global__ __launch_bounds__(256) void attn_gemm(const __bf16* __restrict__ Ah,
                                                 const __bf16* __restrict__ encb,
                                                 float* __restrict__ E) {
  int b = blockIdx.x >> 2, stile = blockIdx.x & 3;
  int wave = threadIdx.x >> 6, lane = threadIdx.x & 63;
  int q = lane >> 4, ln = lane & 15;
  int s = stile * 64 + wave * 16 + ln;
  const __bf16* brow = encb + ((size_t)b * SS_ + s) * HH_;
  const __bf16* arow[3];
#pragma unroll
  for (int mt = 0; mt < 3; ++mt) {
    int tau = mt * 16 + ln; if (tau > 35) tau = 35;
    arow[mt] = Ah + ((size_t)b * TT_ + tau) * HH_;
  }
  f32x4 acc[3] = {};
#pragma unroll 4
  for (int kb = 0; kb < 24; ++kb) {
    int k0 = kb * 32 + q * 8;
    bf16x8 bb = *reinterpret_cast<const bf16x8*>(brow + k0);
#pragma unroll
    for (int mt = 0; mt < 3; ++mt) {
      bf16x8 aa = *reinterpret_cast<const bf16x8*>(arow[mt] + k0);
      acc[mt] = __builtin_amdgcn_mfma_f32_16x16x32_bf16(aa, bb, acc[mt], 0, 0, 0);
    }
  }
#pragma unroll
  for (int mt = 0; mt < 3; ++mt)
#pragma unroll
    for (int r2 = 0; r2 < 4; ++r2) {
      int tau = mt * 16 + q * 4 + r2;
      if (tau < 36) E[((size_t)b * TT_ + tau) * SS_ + s] = acc[mt][r2];
    }
}

// ---------------- masked softmax over S + p_gen ----------------
__global__ __launch_bounds__(256) void softmax_pg(const float* __restrict__ E,
                                                  const int* __restrict__ x,
                                                  const float* __restrict__ encg,
                                                  const __bf16* __restrict__ wsbf,
                                                  const __bf16* __restrict__ Ah,
                                                  const float* __restrict__ wgen,
                                                  const float* __restrict__ wgenb,
                                                  float* __restrict__ attn,
                                                  float* __restrict__ pg) {
  int m = blockIdx.x;
  int b = m / TT_, tau = m - b * TT_;
  int m_in = tau * 32 + b;
  int t = threadIdx.x;
  __shared__ float red[256];
  __shared__ float r1[256], r2[256], r3[256];
  float e = E[(size_t)m * SS_ + t];
  if (x[b * SS_ + t] == 0) e = -1000000000.0f;
  red[t] = e; __syncthreads();
  for (int off = 128; off; off >>= 1) {
    if (t < off) red[t] = fmaxf(red[t], red[t + off]);
    __syncthreads();
  }
  float mx = red[0];
  float p = expf(e - mx);
  float dsum = 0.f;
#pragma unroll
  for (int i = 0; i < 3; ++i) {
    int k = t + i * 256;
    dsum += (float)wsbf[(size_t)m_in * HH_ + k] * wgen[k];
    dsum += (float)Ah[(size_t)m * HH_ + k] * wgen[768 + k];
  }
  float pe = p * encg[b * SS_ + t];
  r1[t] = p; r2[t] = pe; r3[t] = dsum; __syncthreads();
  for (int off = 128; off; off >>= 1) {
    if (t < off) { r1[t] += r1[t + off]; r2[t] += r2[t + off]; r3[t] += r3[t + off]; }
    __syncthreads();
  }
  float Z = r1[0];
  attn[(size_t)m * SS_ + t] = p / Z;
  if (t == 0) pg[m] = sigmoidf_(r3[0] + r2[0] / Z + wgenb[0]);
}

// ---------------- finalize: out = pg/Z * exp_vals (in place) ----------------
__global__ __launch_bounds__(256) void finalize(float* __restrict__ C,
                                                const float* __restrict__ rowsum,
                                                const float* __restrict__ pg) {
  int m = blockIdx.y;
  float scale = pg[m] / rowsum[m];
  int base_i = blockIdx.x * 2048;
  size_t rowb = (size_t)m * VV_;
#pragma unroll
  for (int j = 0; j < 8; ++j) {
    int i = base_i + j * 256 + threadIdx.x;
    if (i < VV_) C[rowb + i] *= scale;
  }
}

// ---------------- pointer scatter ----------------
__global__ __launch_bounds__(256) void scatter_ctx(float* __restrict__ C,
                                                   const float* __restrict__ attn,
                                                   const float* __restrict__ pg,
                                                   const int* __restrict__ x) {
  int m = blockIdx.x, s = threadIdx.x;
  int b = m / TT_;
  float v = (1.f - pg[m]) * attn[(size_t)m * SS_ + s];
  int col = x[b * SS_ + s];
  atomicAdd(C + (size_t)m * VV_ + col, v);
}

extern "C" void kernel_launch(void* const* d_in, const int* in_sizes, int n_in,
                              void* d_out, int out_size, void* d_ws, size_t ws_size,
                              hipStream_t stream) {
  const int*   x       = (const int*)d_in[0];
  const float* dec     = (const float*)d_in[1];
  const float* enc     = (const float*)d_in[2];
  const float* hidden  = (const float*)d_in[3];
  const int*   teacher = (const int*)d_in[5];
  const float* embed   = (const float*)d_in[6];
  const float* wih     = (const float*)d_in[7];
  const float* whh     = (const float*)d_in[8];
  const float* bih     = (const float*)d_in[9];
  const float* bhh     = (const float*)d_in[10];
  const float* wgen    = (const float*)d_in[11];
  const float* wgenb   = (const float*)d_in[12];
  float* out = (float*)d_out;

  char* w = (char*)d_ws;
  __bf16* embed_bf = (__bf16*)w;  w += (size_t)VV_ * HH_ * 2;
  __bf16* enc_bf   = (__bf16*)w;  w += (size_t)BB_ * SS_ * HH_ * 2;
  __bf16* wih_bf   = (__bf16*)w;  w += (size_t)2304 * HH_ * 2;
  __bf16* whh_bf   = (__bf16*)w;  w += (size_t)2304 * HH_ * 2;
  __bf16* ws_bf    = (__bf16*)w;  w += (size_t)MM_ * HH_ * 2;
  __bf16* hid_bf   = (__bf16*)w;  w += (size_t)BB_ * HH_ * 2;
  __bf16* A_h      = (__bf16*)w;  w += (size_t)MM_ * HH_ * 2;
  float*  GI       = (float*)w;   w += (size_t)MM_ * 2304 * 4;
  float*  E        = (float*)w;   w += (size_t)MM_ * SS_ * 4;
  float*  attn     = (float*)w;   w += (size_t)MM_ * SS_ * 4;
  float*  encg     = (float*)w;   w += (size_t)BB_ * SS_ * 4;
  float*  pg       = (float*)w;   w += 8192;
  char*   ctl      = w;           w += 16384;  // rowsum[1152] + flags[96*16]
  __bf16* Hx       = (__bf16*)w;  w += (size_t)2 * BB_ * HH_ * 2;  // h exchange dbuf
  float*    rowsum = (float*)ctl;
  unsigned* flags  = (unsigned*)(ctl + 4864);

  // 0) zero rowsum + flags (ws is re-poisoned 0xAA before every call)
  hipMemsetAsync(ctl, 0, 16384, stream);

  // 1) conversions to bf16
  cvt_bf16<<<(VV_ * HH_ / 4 + 255) / 256, 256, 0, stream>>>(embed, embed_bf, VV_ * HH_ / 4);
  cvt_bf16<<<(BB_ * SS_ * HH_ / 4 + 255) / 256, 256, 0, stream>>>(enc, enc_bf, BB_ * SS_ * HH_ / 4);
  cvt_bf16<<<(2304 * HH_ / 4 + 255) / 256, 256, 0, stream>>>(wih, wih_bf, 2304 * HH_ / 4);
  cvt_bf16<<<(2304 * HH_ / 4 + 255) / 256, 256, 0, stream>>>(whh, whh_bf, 2304 * HH_ / 4);
  cvt_bf16<<<(BB_ * HH_ / 4 + 255) / 256, 256, 0, stream>>>(hidden, hid_bf, BB_ * HH_ / 4);

  // 2) step inputs
  build_ws<<<(MM_ * HH_ + 255) / 256, 256, 0, stream>>>(dec, teacher, embed, ws_bf);

  // 3) GI = ws @ Wih^T : M=1152, N=2304, K=768
  gemm_bt2<0><<<dim3(2304 / 128, MM_ / 128), 256, 0, stream>>>(ws_bf, wih_bf, GI, nullptr, 2304, 2304);

  // 4) encg
  enc_gate<<<BB_ * SS_ / 4, 256, 0, stream>>>(enc, wgen, encg);

  // 5) persistent GRU scan (fence-free: sc1 reads + per-wave flags)
  gru_scan<<<NBLK_GRU, 128, 0, stream>>>(hid_bf, hidden, whh_bf, GI, bih, bhh, A_h, Hx, flags);

  // 6) attention + masked softmax + p_gen
  attn_gemm<<<BB_ * 4, 256, 0, stream>>>(A_h, enc_bf, E);
  softmax_pg<<<MM_, 256, 0, stream>>>(E, x, encg, ws_bf, A_h, wgen, wgenb, attn, pg);

  // 7) vocab logits -> exp into d_out + atomic row sums
  gemm_bt2<1><<<dim3((VV_ + 127) / 128, MM_ / 128), 256, 0, stream>>>(A_h, embed_bf, out, rowsum, VV_, VV_);

  // 8) scale by pg/Z in place, then pointer scatter
  finalize<<<dim3((VV_ + 2047) / 2048, MM_), 256, 0, stream>>>(out, rowsum, pg);
  scatter_ctx<<<MM_, 256, 0, stream>>>(out, attn, pg, x);
}